// Round 18
// baseline (546.568 us; speedup 1.0000x reference)
//
#include <hip/hip_runtime.h>
#include <hip/hip_bf16.h>
#include <hip/hip_fp16.h>

#define N_NODES 100000
#define N_EDGES 3200000
#define HID 64
#define GDIM 32
#define NUM_GRAPHS 16
#define NB1 256      // coarse buckets (dst >> 9)
#define BSHIFT 9
#define B1 512       // blocks in pass-1 kernels

// ---------- helpers ----------
__device__ __forceinline__ unsigned fkey(float f) {
    unsigned u = __float_as_uint(f);
    return (u & 0x80000000u) ? ~u : (u | 0x80000000u);
}
__device__ __forceinline__ float funkey(unsigned k) {
    unsigned u = (k & 0x80000000u) ? (k ^ 0x80000000u) : ~k;
    return __uint_as_float(u);
}

struct half4 { __half2 lo, hi; };
struct __align__(16) half8 { __half2 a, b, c, d; };

// ---------- CSR build: two-level bucket sort, LDS atomics only ----------
__global__ __launch_bounds__(256) void hist1_kernel(const int* __restrict__ dst, int* __restrict__ h1, int E4) {
    __shared__ int h[NB1];
    int t = threadIdx.x, b = blockIdx.x;
    h[t] = 0;
    __syncthreads();
    for (int i = b * 256 + t; i < E4; i += B1 * 256) {
        int4 d = ((const int4*)dst)[i];
        atomicAdd(&h[d.x >> BSHIFT], 1);
        atomicAdd(&h[d.y >> BSHIFT], 1);
        atomicAdd(&h[d.z >> BSHIFT], 1);
        atomicAdd(&h[d.w >> BSHIFT], 1);
    }
    __syncthreads();
    h1[b * NB1 + t] = h[t];
}

__global__ __launch_bounds__(256) void scan1_kernel(const int* __restrict__ h1, int* __restrict__ off1,
                                                    int* __restrict__ bstart, int E) {
    __shared__ int ts[256];
    int t = threadIdx.x;
    int tot = 0;
    for (int k = 0; k < B1; k++) tot += h1[k * NB1 + t];
    ts[t] = tot;
    __syncthreads();
    for (int off = 1; off < 256; off <<= 1) {
        int v = (t >= off) ? ts[t - off] : 0;
        __syncthreads();
        ts[t] += v;
        __syncthreads();
    }
    int base = ts[t] - tot;          // exclusive bucket base (in edges)
    bstart[t] = base;
    if (t == 255) bstart[256] = E;
    int run = base;
    for (int k = 0; k < B1; k++) { off1[k * NB1 + t] = run; run += h1[k * NB1 + t]; }
}

// pass 1c: scatter packed (src<<9 | dst&511) into coarse-bucket order
__global__ __launch_bounds__(256) void scatter1_kernel(const int* __restrict__ src, const int* __restrict__ dst,
                                                       const int* __restrict__ off1, int* __restrict__ pairs, int E4) {
    __shared__ int cur[NB1];
    int t = threadIdx.x, b = blockIdx.x;
    cur[t] = off1[b * NB1 + t];
    __syncthreads();
    for (int i = b * 256 + t; i < E4; i += B1 * 256) {
        int4 d = ((const int4*)dst)[i];
        int4 s = ((const int4*)src)[i];
        int p0 = atomicAdd(&cur[d.x >> BSHIFT], 1);
        int p1 = atomicAdd(&cur[d.y >> BSHIFT], 1);
        int p2 = atomicAdd(&cur[d.z >> BSHIFT], 1);
        int p3 = atomicAdd(&cur[d.w >> BSHIFT], 1);
        pairs[p0] = (s.x << BSHIFT) | (d.x & 511);
        pairs[p1] = (s.y << BSHIFT) | (d.y & 511);
        pairs[p2] = (s.z << BSHIFT) | (d.z & 511);
        pairs[p3] = (s.w << BSHIFT) | (d.w & 511);
    }
}

__global__ __launch_bounds__(256) void bucket_csr_kernel(const int* __restrict__ pairs, const int* __restrict__ bstart,
                                                         int* __restrict__ rowstart, int* __restrict__ csr,
                                                         int N, int E) {
    __shared__ int hist[512];
    __shared__ int ts[256];
    int b = blockIdx.x, t = threadIdx.x;
    int estart = bstart[b], eend = bstart[b + 1];
    hist[t] = 0; hist[t + 256] = 0;
    __syncthreads();
    for (int e = estart + t; e < eend; e += 256) {
        int pr = pairs[e];
        atomicAdd(&hist[pr & 511], 1);
    }
    __syncthreads();
    int a0 = hist[2 * t], a1 = hist[2 * t + 1];
    int s = a0 + a1;
    ts[t] = s;
    __syncthreads();
    for (int off = 1; off < 256; off <<= 1) {
        int v = (t >= off) ? ts[t - off] : 0;
        __syncthreads();
        ts[t] += v;
        __syncthreads();
    }
    int excl = ts[t] - s;   // exclusive over this bucket's pairs
    __syncthreads();
    hist[2 * t]     = estart + excl;        // cursors
    hist[2 * t + 1] = estart + excl + a0;
    int nb0 = b << BSHIFT;
    int i0 = nb0 + 2 * t, i1 = i0 + 1;
    if (i0 < N) rowstart[i0] = estart + excl;
    if (i1 < N) rowstart[i1] = estart + excl + a0;
    if (b == gridDim.x - 1 && t == 0) rowstart[N] = E;
    __syncthreads();
    for (int e = estart + t; e < eend; e += 256) {
        int pr = pairs[e];
        int p = atomicAdd(&hist[pr & 511], 1);
        csr[p] = pr >> BSHIFT;
    }
}

// ---------- lin0: y = x @ W + b  (N x 64), also emits fp16 copy ----------
__global__ __launch_bounds__(256) void lin0_kernel(const float* __restrict__ x, const float* __restrict__ W,
                            const float* __restrict__ b, float* __restrict__ y, __half* __restrict__ yh, int N) {
    __shared__ __align__(16) float Wl[64 * 64];
    __shared__ float bl[64];
    int t = threadIdx.x;
    for (int i = t; i < 64 * 64; i += 256) Wl[i] = W[i];
    if (t < 64) bl[t] = b[t];
    __syncthreads();
    int row = blockIdx.x * 256 + t;
    if (row >= N) return;
    float acc[64];
#pragma unroll
    for (int j = 0; j < 64; j++) acc[j] = bl[j];
    const float4* xr = (const float4*)(x + (size_t)row * 64);
#pragma unroll
    for (int c = 0; c < 16; c++) {
        float4 xv = xr[c];
        float xs[4] = {xv.x, xv.y, xv.z, xv.w};
#pragma unroll
        for (int kk = 0; kk < 4; kk++) {
            int k = c * 4 + kk;
#pragma unroll
            for (int j4 = 0; j4 < 16; j4++) {
                float4 w = *(const float4*)&Wl[k * 64 + j4 * 4];
                acc[j4 * 4 + 0] += xs[kk] * w.x;
                acc[j4 * 4 + 1] += xs[kk] * w.y;
                acc[j4 * 4 + 2] += xs[kk] * w.z;
                acc[j4 * 4 + 3] += xs[kk] * w.w;
            }
        }
    }
    float4* yr = (float4*)(y + (size_t)row * 64);
#pragma unroll
    for (int c = 0; c < 16; c++)
        yr[c] = make_float4(acc[c * 4], acc[c * 4 + 1], acc[c * 4 + 2], acc[c * 4 + 3]);
    __half2* hr = (__half2*)(yh + (size_t)row * 64);
#pragma unroll
    for (int c = 0; c < 32; c++)
        hr[c] = __halves2half2(__float2half_rn(acc[c * 2]), __float2half_rn(acc[c * 2 + 1]));
}

// ---------- mean aggregation from fp16 table: one wave per node, 8 edges x 8 lanes x half8 ----------
__global__ __launch_bounds__(256) void agg_kernel(const __half* __restrict__ xh, const int* __restrict__ rowstart,
                           const int* __restrict__ csr, float* __restrict__ meanout, int N) {
    int wid = threadIdx.x >> 6, lane = threadIdx.x & 63;
    int node = blockIdx.x * 4 + wid;
    if (node >= N) return;
    int ro = rowstart[node], re = rowstart[node + 1];
    int g = lane >> 3, c8 = lane & 7;      // 8 edge-groups, 8 lanes per row (16B each)
    float acc[8];
#pragma unroll
    for (int j = 0; j < 8; j++) acc[j] = 0.f;
    for (int base = ro; base < re; base += 64) {
        int rem = re - base;
        int idx = 0;
        if (lane < rem) idx = csr[base + lane];
        int kmax = rem < 64 ? rem : 64;
        for (int k = 0; k < kmax; k += 8) {
            int e = k + g;
            int s = __shfl(idx, e);
            if (e < kmax) {
                half8 hv = *(const half8*)(xh + (size_t)s * 64 + (c8 << 3));
                float2 f0 = __half22float2(hv.a);
                float2 f1 = __half22float2(hv.b);
                float2 f2 = __half22float2(hv.c);
                float2 f3 = __half22float2(hv.d);
                acc[0] += f0.x; acc[1] += f0.y; acc[2] += f1.x; acc[3] += f1.y;
                acc[4] += f2.x; acc[5] += f2.y; acc[6] += f3.x; acc[7] += f3.y;
            }
        }
    }
#pragma unroll
    for (int off = 8; off < 64; off <<= 1) {
#pragma unroll
        for (int j = 0; j < 8; j++) acc[j] += __shfl_xor(acc[j], off);
    }
    int deg = re - ro;
    float inv = 1.0f / (float)(deg > 0 ? deg : 1);
    if (lane < 8) {
        float4* mr = (float4*)(meanout + (size_t)node * 64 + (c8 << 3));
        mr[0] = make_float4(acc[0] * inv, acc[1] * inv, acc[2] * inv, acc[3] * inv);
        mr[1] = make_float4(acc[4] * inv, acc[5] * inv, acc[6] * inv, acc[7] * inv);
    }
}

// ---------- sage: xout = mean @ LW + lb + xin @ RW (optional fp16 copy) ----------
__global__ __launch_bounds__(256) void sage_kernel(const float* __restrict__ mean, const float* __restrict__ xin,
                            const float* __restrict__ lw, const float* __restrict__ lb,
                            const float* __restrict__ rw, float* __restrict__ xout,
                            __half* __restrict__ xhout, int N) {
    __shared__ __align__(16) float LW[64 * 64];
    __shared__ __align__(16) float RW[64 * 64];
    __shared__ float LB[64];
    int t = threadIdx.x;
    for (int i = t; i < 64 * 64; i += 256) { LW[i] = lw[i]; RW[i] = rw[i]; }
    if (t < 64) LB[t] = lb[t];
    __syncthreads();
    int row = blockIdx.x * 256 + t;
    if (row >= N) return;
    float acc[64];
#pragma unroll
    for (int j = 0; j < 64; j++) acc[j] = LB[j];
    const float4* mr = (const float4*)(mean + (size_t)row * 64);
    const float4* xr = (const float4*)(xin + (size_t)row * 64);
#pragma unroll
    for (int c = 0; c < 16; c++) {
        float4 xv = mr[c];
        float xs[4] = {xv.x, xv.y, xv.z, xv.w};
#pragma unroll
        for (int kk = 0; kk < 4; kk++) {
            int k = c * 4 + kk;
#pragma unroll
            for (int j4 = 0; j4 < 16; j4++) {
                float4 w = *(const float4*)&LW[k * 64 + j4 * 4];
                acc[j4 * 4 + 0] += xs[kk] * w.x;
                acc[j4 * 4 + 1] += xs[kk] * w.y;
                acc[j4 * 4 + 2] += xs[kk] * w.z;
                acc[j4 * 4 + 3] += xs[kk] * w.w;
            }
        }
    }
#pragma unroll
    for (int c = 0; c < 16; c++) {
        float4 xv = xr[c];
        float xs[4] = {xv.x, xv.y, xv.z, xv.w};
#pragma unroll
        for (int kk = 0; kk < 4; kk++) {
            int k = c * 4 + kk;
#pragma unroll
            for (int j4 = 0; j4 < 16; j4++) {
                float4 w = *(const float4*)&RW[k * 64 + j4 * 4];
                acc[j4 * 4 + 0] += xs[kk] * w.x;
                acc[j4 * 4 + 1] += xs[kk] * w.y;
                acc[j4 * 4 + 2] += xs[kk] * w.z;
                acc[j4 * 4 + 3] += xs[kk] * w.w;
            }
        }
    }
    float4* yr = (float4*)(xout + (size_t)row * 64);
#pragma unroll
    for (int c = 0; c < 16; c++)
        yr[c] = make_float4(acc[c * 4], acc[c * 4 + 1], acc[c * 4 + 2], acc[c * 4 + 3]);
    if (xhout) {
        __half2* hr = (__half2*)(xhout + (size_t)row * 64);
#pragma unroll
        for (int c = 0; c < 32; c++)
            hr[c] = __halves2half2(__float2half_rn(acc[c * 2]), __float2half_rn(acc[c * 2 + 1]));
    }
}

// ---------- head: hop-parallel, 768 threads (thread = node x hop), LDS xc combine ----------
__global__ __launch_bounds__(768) void head_kernel(const float* __restrict__ x0, const float* __restrict__ x1,
                            const float* __restrict__ x2, const int* __restrict__ batch,
                            const float* __restrict__ e0w, const float* __restrict__ e0b,
                            const float* __restrict__ e1w, const float* __restrict__ e1b,
                            const float* __restrict__ e2w, const float* __restrict__ e2b,
                            const float* __restrict__ mw, const float* __restrict__ mb,
                            const float* __restrict__ gw, const float* __restrict__ gbp,
                            const float* __restrict__ vw, const float* __restrict__ vb,
                            float* __restrict__ gout, float* __restrict__ vout,
                            unsigned* __restrict__ mkey, int N) {
    __shared__ __align__(16) float EW[3 * 2048];
    __shared__ __align__(16) float MW[96 * 32];
    __shared__ __align__(16) float VW[32 * 32];
    __shared__ float EB[96], MB[32], GW[32], VB[32];
    __shared__ float GB;
    __shared__ float XC[256][33];        // +1 pad: spread banks for atomic combine
    __shared__ unsigned smax[16];
    int t = threadIdx.x;
    for (int i = t; i < 2048; i += 768) { EW[i] = e0w[i]; EW[2048 + i] = e1w[i]; EW[4096 + i] = e2w[i]; }
    for (int i = t; i < 3072; i += 768) MW[i] = mw[i];
    for (int i = t; i < 1024; i += 768) VW[i] = vw[i];
    if (t < 32) { EB[t] = e0b[t]; EB[32 + t] = e1b[t]; EB[64 + t] = e2b[t];
                  MB[t] = mb[t]; GW[t] = gw[t]; VB[t] = vb[t]; }
    if (t == 0) GB = gbp[0];
    if (t < 16) smax[t] = 0u;
    for (int i = t; i < 256 * 33; i += 768) ((float*)XC)[i] = 0.f;
    __syncthreads();
    int sub = t & 255, h = t >> 8;       // node-in-block, hop
    int node = blockIdx.x * 256 + sub;
    if (node < N) {
        const float* xsrc = (h == 0) ? x0 : (h == 1) ? x1 : x2;
        float e[32];
#pragma unroll
        for (int j = 0; j < 32; j++) e[j] = EB[h * 32 + j];
        const float4* xr = (const float4*)(xsrc + (size_t)node * 64);
#pragma unroll
        for (int c = 0; c < 16; c++) {
            float4 xv = xr[c];
            float xs[4] = {xv.x, xv.y, xv.z, xv.w};
#pragma unroll
            for (int kk = 0; kk < 4; kk++) {
                int k = c * 4 + kk;
#pragma unroll
                for (int j4 = 0; j4 < 8; j4++) {
                    float4 w = *(const float4*)&EW[h * 2048 + k * 32 + j4 * 4];
                    e[j4 * 4 + 0] += xs[kk] * w.x;
                    e[j4 * 4 + 1] += xs[kk] * w.y;
                    e[j4 * 4 + 2] += xs[kk] * w.z;
                    e[j4 * 4 + 3] += xs[kk] * w.w;
                }
            }
        }
#pragma unroll
        for (int j = 0; j < 32; j++) e[j] = fmaxf(e[j], 0.f);
        float mc[32];
#pragma unroll
        for (int j = 0; j < 32; j++) mc[j] = 0.f;
#pragma unroll
        for (int i = 0; i < 32; i++) {
#pragma unroll
            for (int j4 = 0; j4 < 8; j4++) {
                float4 w = *(const float4*)&MW[(h * 32 + i) * 32 + j4 * 4];
                mc[j4 * 4 + 0] += e[i] * w.x;
                mc[j4 * 4 + 1] += e[i] * w.y;
                mc[j4 * 4 + 2] += e[i] * w.z;
                mc[j4 * 4 + 3] += e[i] * w.w;
            }
        }
#pragma unroll
        for (int j = 0; j < 32; j++) atomicAdd(&XC[sub][j], mc[j]);
    }
    __syncthreads();
    if (h == 0 && node < N) {
        float xc[32];
#pragma unroll
        for (int j = 0; j < 32; j++) xc[j] = fmaxf(XC[sub][j] + MB[j], 0.f);
        float g = GB;
#pragma unroll
        for (int i = 0; i < 32; i++) g += xc[i] * GW[i];
        float vv[32];
#pragma unroll
        for (int j = 0; j < 32; j++) vv[j] = VB[j];
#pragma unroll
        for (int i = 0; i < 32; i++) {
#pragma unroll
            for (int j4 = 0; j4 < 8; j4++) {
                float4 w = *(const float4*)&VW[i * 32 + j4 * 4];
                vv[j4 * 4 + 0] += xc[i] * w.x;
                vv[j4 * 4 + 1] += xc[i] * w.y;
                vv[j4 * 4 + 2] += xc[i] * w.z;
                vv[j4 * 4 + 3] += xc[i] * w.w;
            }
        }
        gout[node] = g;
        float4* vr = (float4*)(vout + (size_t)node * 32);
#pragma unroll
        for (int c = 0; c < 8; c++)
            vr[c] = make_float4(vv[c * 4], vv[c * 4 + 1], vv[c * 4 + 2], vv[c * 4 + 3]);
        atomicMax(&smax[batch[node]], fkey(g));
    }
    __syncthreads();
    if (t < 16) atomicMax(&mkey[t], smax[t]);
}

// ---------- pool: d = seg_sum(e), num = seg_sum(e*v) ----------
__global__ __launch_bounds__(256) void pool_kernel(const float* __restrict__ g, const float* __restrict__ v,
                            const int* __restrict__ batch, const unsigned* __restrict__ mkey,
                            float* __restrict__ dsum, float* __restrict__ pooled, int N) {
    __shared__ float sd[16];
    __shared__ float sp[16 * 32];
    __shared__ float sm[16];
    int t = threadIdx.x;
    if (t < 16) { sd[t] = 0.f; sm[t] = funkey(mkey[t]); }
    for (int i = t; i < 512; i += 256) sp[i] = 0.f;
    __syncthreads();
    int node = blockIdx.x * 256 + t;
    if (node < N) {
        int b = batch[node];
        float e = __expf(g[node] - sm[b]);
        atomicAdd(&sd[b], e);
        const float4* vr = (const float4*)(v + (size_t)node * 32);
#pragma unroll
        for (int c = 0; c < 8; c++) {
            float4 vv = vr[c];
            atomicAdd(&sp[b * 32 + c * 4 + 0], e * vv.x);
            atomicAdd(&sp[b * 32 + c * 4 + 1], e * vv.y);
            atomicAdd(&sp[b * 32 + c * 4 + 2], e * vv.z);
            atomicAdd(&sp[b * 32 + c * 4 + 3], e * vv.w);
        }
    }
    __syncthreads();
    if (t < 16) atomicAdd(&dsum[t], sd[t]);
    for (int i = t; i < 512; i += 256) atomicAdd(&pooled[i], sp[i]);
}

// ---------- final: logits + softmax ----------
__global__ __launch_bounds__(64) void final_kernel(const float* __restrict__ dsum, const float* __restrict__ pooled,
                             const float* __restrict__ ow, const float* __restrict__ ob,
                             float* __restrict__ out) {
    int t = threadIdx.x;
    if (t >= 16) return;
    float d = dsum[t];
    float l0 = ob[0], l1 = ob[1];
    for (int i = 0; i < 32; i++) {
        float p = pooled[t * 32 + i] / d;
        l0 += p * ow[i * 2 + 0];
        l1 += p * ow[i * 2 + 1];
    }
    float m = fmaxf(l0, l1);
    float e0 = __expf(l0 - m), e1 = __expf(l1 - m);
    float s = e0 + e1;
    out[t * 2 + 0] = e0 / s;
    out[t * 2 + 1] = e1 / s;
    out[32 + t * 2 + 0] = l0;
    out[32 + t * 2 + 1] = l1;
}

extern "C" void kernel_launch(void* const* d_in, const int* in_sizes, int n_in,
                              void* d_out, int out_size, void* d_ws, size_t ws_size,
                              hipStream_t stream) {
    const float* x       = (const float*)d_in[0];
    const int*   ei      = (const int*)d_in[1];
    const int*   batch   = (const int*)d_in[2];
    const float* lin0_w  = (const float*)d_in[3];
    const float* lin0_b  = (const float*)d_in[4];
    const float* s1_lw   = (const float*)d_in[5];
    const float* s1_lb   = (const float*)d_in[6];
    const float* s1_rw   = (const float*)d_in[7];
    const float* s2_lw   = (const float*)d_in[8];
    const float* s2_lb   = (const float*)d_in[9];
    const float* s2_rw   = (const float*)d_in[10];
    const float* e0w     = (const float*)d_in[11];
    const float* e0b     = (const float*)d_in[12];
    const float* e1w     = (const float*)d_in[13];
    const float* e1b     = (const float*)d_in[14];
    const float* e2w     = (const float*)d_in[15];
    const float* e2b     = (const float*)d_in[16];
    const float* mw      = (const float*)d_in[17];
    const float* mb      = (const float*)d_in[18];
    const float* gw      = (const float*)d_in[19];
    const float* gb      = (const float*)d_in[20];
    const float* vw      = (const float*)d_in[21];
    const float* vb      = (const float*)d_in[22];
    const float* ow      = (const float*)d_in[23];
    const float* ob      = (const float*)d_in[24];
    float* out = (float*)d_out;

    const int N = N_NODES, E = N_EDGES;
    const int* src = ei;
    const int* dst = ei + E;

    // workspace carve
    char* p = (char*)d_ws;
    auto carve = [&](size_t bytes) { char* r = p; p += (bytes + 255) & ~(size_t)255; return (void*)r; };
    float* x0      = (float*)carve((size_t)N * 64 * 4);
    float* x1      = (float*)carve((size_t)N * 64 * 4);
    float* x2      = (float*)carve((size_t)N * 64 * 4);
    __half* x0h    = (__half*)carve((size_t)N * 64 * 2);
    __half* x1h    = (__half*)carve((size_t)N * 64 * 2);
    float* meanb   = (float*)carve((size_t)N * 64 * 4);
    float* vbuf    = (float*)carve((size_t)N * 32 * 4);
    float* gbuf    = (float*)carve((size_t)N * 4);
    int*   csr     = (int*)carve((size_t)E * 4);
    int*   pairs   = (int*)carve((size_t)E * 4);
    int*   h1      = (int*)carve((size_t)B1 * NB1 * 4);
    int*   off1    = (int*)carve((size_t)B1 * NB1 * 4);
    int*   bstart  = (int*)carve((NB1 + 1) * 4);
    int*   rowstart= (int*)carve((size_t)(N + 1) * 4);
    unsigned* mkey = (unsigned*)carve(16 * 4);
    float* dsum    = (float*)carve(16 * 4);
    float* pooled  = (float*)carve(16 * 32 * 4);

    hipMemsetAsync(mkey, 0, 16 * 4, stream);
    hipMemsetAsync(dsum, 0, 16 * 4, stream);
    hipMemsetAsync(pooled, 0, 16 * 32 * 4, stream);

    const int E4 = E / 4;                 // E divisible by 4
    int nbl = (N + 255) / 256;
    int abl = (N + 3) / 4;
    const int NBUCK = (N + 511) >> BSHIFT;   // 196

    hist1_kernel<<<B1, 256, 0, stream>>>(dst, h1, E4);
    scan1_kernel<<<1, 256, 0, stream>>>(h1, off1, bstart, E);
    scatter1_kernel<<<B1, 256, 0, stream>>>(src, dst, off1, pairs, E4);
    bucket_csr_kernel<<<NBUCK, 256, 0, stream>>>(pairs, bstart, rowstart, csr, N, E);

    lin0_kernel<<<nbl, 256, 0, stream>>>(x, lin0_w, lin0_b, x0, x0h, N);

    agg_kernel<<<abl, 256, 0, stream>>>(x0h, rowstart, csr, meanb, N);
    sage_kernel<<<nbl, 256, 0, stream>>>(meanb, x0, s1_lw, s1_lb, s1_rw, x1, x1h, N);

    agg_kernel<<<abl, 256, 0, stream>>>(x1h, rowstart, csr, meanb, N);
    sage_kernel<<<nbl, 256, 0, stream>>>(meanb, x1, s2_lw, s2_lb, s2_rw, x2, (__half*)nullptr, N);

    head_kernel<<<nbl, 768, 0, stream>>>(x0, x1, x2, batch,
                                         e0w, e0b, e1w, e1b, e2w, e2b,
                                         mw, mb, gw, gb, vw, vb,
                                         gbuf, vbuf, mkey, N);

    pool_kernel<<<nbl, 256, 0, stream>>>(gbuf, vbuf, batch, mkey, dsum, pooled, N);

    final_kernel<<<1, 64, 0, stream>>>(dsum, pooled, ow, ob, out);
}

// Round 19
// 507.507 us; speedup vs baseline: 1.0770x; 1.0770x over previous
//
#include <hip/hip_runtime.h>
#include <hip/hip_bf16.h>
#include <hip/hip_fp16.h>

#define N_NODES 100000
#define N_EDGES 3200000
#define HID 64
#define GDIM 32
#define NUM_GRAPHS 16
#define NB1 256      // coarse buckets (dst >> 9)
#define BSHIFT 9
#define B1 512       // blocks in pass-1 kernels

// ---------- helpers ----------
__device__ __forceinline__ unsigned fkey(float f) {
    unsigned u = __float_as_uint(f);
    return (u & 0x80000000u) ? ~u : (u | 0x80000000u);
}
__device__ __forceinline__ float funkey(unsigned k) {
    unsigned u = (k & 0x80000000u) ? (k ^ 0x80000000u) : ~k;
    return __uint_as_float(u);
}

struct half4 { __half2 lo, hi; };
struct __align__(16) half8 { __half2 a, b, c, d; };

// ---------- CSR build: two-level bucket sort, LDS atomics only ----------
__global__ __launch_bounds__(256) void hist1_kernel(const int* __restrict__ dst, int* __restrict__ h1, int E4) {
    __shared__ int h[NB1];
    int t = threadIdx.x, b = blockIdx.x;
    h[t] = 0;
    __syncthreads();
    for (int i = b * 256 + t; i < E4; i += B1 * 256) {
        int4 d = ((const int4*)dst)[i];
        atomicAdd(&h[d.x >> BSHIFT], 1);
        atomicAdd(&h[d.y >> BSHIFT], 1);
        atomicAdd(&h[d.z >> BSHIFT], 1);
        atomicAdd(&h[d.w >> BSHIFT], 1);
    }
    __syncthreads();
    h1[b * NB1 + t] = h[t];
}

__global__ __launch_bounds__(256) void scan1_kernel(const int* __restrict__ h1, int* __restrict__ off1,
                                                    int* __restrict__ bstart, int E) {
    __shared__ int ts[256];
    int t = threadIdx.x;
    int tot = 0;
    for (int k = 0; k < B1; k++) tot += h1[k * NB1 + t];
    ts[t] = tot;
    __syncthreads();
    for (int off = 1; off < 256; off <<= 1) {
        int v = (t >= off) ? ts[t - off] : 0;
        __syncthreads();
        ts[t] += v;
        __syncthreads();
    }
    int base = ts[t] - tot;          // exclusive bucket base (in edges)
    bstart[t] = base;
    if (t == 255) bstart[256] = E;
    int run = base;
    for (int k = 0; k < B1; k++) { off1[k * NB1 + t] = run; run += h1[k * NB1 + t]; }
}

// pass 1c: scatter packed (src<<9 | dst&511) into coarse-bucket order
__global__ __launch_bounds__(256) void scatter1_kernel(const int* __restrict__ src, const int* __restrict__ dst,
                                                       const int* __restrict__ off1, int* __restrict__ pairs, int E4) {
    __shared__ int cur[NB1];
    int t = threadIdx.x, b = blockIdx.x;
    cur[t] = off1[b * NB1 + t];
    __syncthreads();
    for (int i = b * 256 + t; i < E4; i += B1 * 256) {
        int4 d = ((const int4*)dst)[i];
        int4 s = ((const int4*)src)[i];
        int p0 = atomicAdd(&cur[d.x >> BSHIFT], 1);
        int p1 = atomicAdd(&cur[d.y >> BSHIFT], 1);
        int p2 = atomicAdd(&cur[d.z >> BSHIFT], 1);
        int p3 = atomicAdd(&cur[d.w >> BSHIFT], 1);
        pairs[p0] = (s.x << BSHIFT) | (d.x & 511);
        pairs[p1] = (s.y << BSHIFT) | (d.y & 511);
        pairs[p2] = (s.z << BSHIFT) | (d.z & 511);
        pairs[p3] = (s.w << BSHIFT) | (d.w & 511);
    }
}

__global__ __launch_bounds__(256) void bucket_csr_kernel(const int* __restrict__ pairs, const int* __restrict__ bstart,
                                                         int* __restrict__ rowstart, int* __restrict__ csr,
                                                         int N, int E) {
    __shared__ int hist[512];
    __shared__ int ts[256];
    int b = blockIdx.x, t = threadIdx.x;
    int estart = bstart[b], eend = bstart[b + 1];
    hist[t] = 0; hist[t + 256] = 0;
    __syncthreads();
    for (int e = estart + t; e < eend; e += 256) {
        int pr = pairs[e];
        atomicAdd(&hist[pr & 511], 1);
    }
    __syncthreads();
    int a0 = hist[2 * t], a1 = hist[2 * t + 1];
    int s = a0 + a1;
    ts[t] = s;
    __syncthreads();
    for (int off = 1; off < 256; off <<= 1) {
        int v = (t >= off) ? ts[t - off] : 0;
        __syncthreads();
        ts[t] += v;
        __syncthreads();
    }
    int excl = ts[t] - s;   // exclusive over this bucket's pairs
    __syncthreads();
    hist[2 * t]     = estart + excl;        // cursors
    hist[2 * t + 1] = estart + excl + a0;
    int nb0 = b << BSHIFT;
    int i0 = nb0 + 2 * t, i1 = i0 + 1;
    if (i0 < N) rowstart[i0] = estart + excl;
    if (i1 < N) rowstart[i1] = estart + excl + a0;
    if (b == gridDim.x - 1 && t == 0) rowstart[N] = E;
    __syncthreads();
    for (int e = estart + t; e < eend; e += 256) {
        int pr = pairs[e];
        int p = atomicAdd(&hist[pr & 511], 1);
        csr[p] = pr >> BSHIFT;
    }
}

// ---------- lin0: y = x @ W + b  (N x 64), also emits fp16 copy ----------
__global__ __launch_bounds__(256) void lin0_kernel(const float* __restrict__ x, const float* __restrict__ W,
                            const float* __restrict__ b, float* __restrict__ y, __half* __restrict__ yh, int N) {
    __shared__ __align__(16) float Wl[64 * 64];
    __shared__ float bl[64];
    int t = threadIdx.x;
    for (int i = t; i < 64 * 64; i += 256) Wl[i] = W[i];
    if (t < 64) bl[t] = b[t];
    __syncthreads();
    int row = blockIdx.x * 256 + t;
    if (row >= N) return;
    float acc[64];
#pragma unroll
    for (int j = 0; j < 64; j++) acc[j] = bl[j];
    const float4* xr = (const float4*)(x + (size_t)row * 64);
#pragma unroll
    for (int c = 0; c < 16; c++) {
        float4 xv = xr[c];
        float xs[4] = {xv.x, xv.y, xv.z, xv.w};
#pragma unroll
        for (int kk = 0; kk < 4; kk++) {
            int k = c * 4 + kk;
#pragma unroll
            for (int j4 = 0; j4 < 16; j4++) {
                float4 w = *(const float4*)&Wl[k * 64 + j4 * 4];
                acc[j4 * 4 + 0] += xs[kk] * w.x;
                acc[j4 * 4 + 1] += xs[kk] * w.y;
                acc[j4 * 4 + 2] += xs[kk] * w.z;
                acc[j4 * 4 + 3] += xs[kk] * w.w;
            }
        }
    }
    float4* yr = (float4*)(y + (size_t)row * 64);
#pragma unroll
    for (int c = 0; c < 16; c++)
        yr[c] = make_float4(acc[c * 4], acc[c * 4 + 1], acc[c * 4 + 2], acc[c * 4 + 3]);
    __half2* hr = (__half2*)(yh + (size_t)row * 64);
#pragma unroll
    for (int c = 0; c < 32; c++)
        hr[c] = __halves2half2(__float2half_rn(acc[c * 2]), __float2half_rn(acc[c * 2 + 1]));
}

// ---------- mean aggregation from fp16 table: one wave per node, 8 edges x 8 lanes x half8 ----------
__global__ __launch_bounds__(256) void agg_kernel(const __half* __restrict__ xh, const int* __restrict__ rowstart,
                           const int* __restrict__ csr, float* __restrict__ meanout, int N) {
    int wid = threadIdx.x >> 6, lane = threadIdx.x & 63;
    int node = blockIdx.x * 4 + wid;
    if (node >= N) return;
    int ro = rowstart[node], re = rowstart[node + 1];
    int g = lane >> 3, c8 = lane & 7;      // 8 edge-groups, 8 lanes per row (16B each)
    float acc[8];
#pragma unroll
    for (int j = 0; j < 8; j++) acc[j] = 0.f;
    for (int base = ro; base < re; base += 64) {
        int rem = re - base;
        int idx = 0;
        if (lane < rem) idx = csr[base + lane];
        int kmax = rem < 64 ? rem : 64;
        for (int k = 0; k < kmax; k += 8) {
            int e = k + g;
            int s = __shfl(idx, e);
            if (e < kmax) {
                half8 hv = *(const half8*)(xh + (size_t)s * 64 + (c8 << 3));
                float2 f0 = __half22float2(hv.a);
                float2 f1 = __half22float2(hv.b);
                float2 f2 = __half22float2(hv.c);
                float2 f3 = __half22float2(hv.d);
                acc[0] += f0.x; acc[1] += f0.y; acc[2] += f1.x; acc[3] += f1.y;
                acc[4] += f2.x; acc[5] += f2.y; acc[6] += f3.x; acc[7] += f3.y;
            }
        }
    }
#pragma unroll
    for (int off = 8; off < 64; off <<= 1) {
#pragma unroll
        for (int j = 0; j < 8; j++) acc[j] += __shfl_xor(acc[j], off);
    }
    int deg = re - ro;
    float inv = 1.0f / (float)(deg > 0 ? deg : 1);
    if (lane < 8) {
        float4* mr = (float4*)(meanout + (size_t)node * 64 + (c8 << 3));
        mr[0] = make_float4(acc[0] * inv, acc[1] * inv, acc[2] * inv, acc[3] * inv);
        mr[1] = make_float4(acc[4] * inv, acc[5] * inv, acc[6] * inv, acc[7] * inv);
    }
}

// ---------- sage: xout = mean @ LW + lb + xin @ RW (optional fp16 copy) ----------
__global__ __launch_bounds__(256) void sage_kernel(const float* __restrict__ mean, const float* __restrict__ xin,
                            const float* __restrict__ lw, const float* __restrict__ lb,
                            const float* __restrict__ rw, float* __restrict__ xout,
                            __half* __restrict__ xhout, int N) {
    __shared__ __align__(16) float LW[64 * 64];
    __shared__ __align__(16) float RW[64 * 64];
    __shared__ float LB[64];
    int t = threadIdx.x;
    for (int i = t; i < 64 * 64; i += 256) { LW[i] = lw[i]; RW[i] = rw[i]; }
    if (t < 64) LB[t] = lb[t];
    __syncthreads();
    int row = blockIdx.x * 256 + t;
    if (row >= N) return;
    float acc[64];
#pragma unroll
    for (int j = 0; j < 64; j++) acc[j] = LB[j];
    const float4* mr = (const float4*)(mean + (size_t)row * 64);
    const float4* xr = (const float4*)(xin + (size_t)row * 64);
#pragma unroll
    for (int c = 0; c < 16; c++) {
        float4 xv = mr[c];
        float xs[4] = {xv.x, xv.y, xv.z, xv.w};
#pragma unroll
        for (int kk = 0; kk < 4; kk++) {
            int k = c * 4 + kk;
#pragma unroll
            for (int j4 = 0; j4 < 16; j4++) {
                float4 w = *(const float4*)&LW[k * 64 + j4 * 4];
                acc[j4 * 4 + 0] += xs[kk] * w.x;
                acc[j4 * 4 + 1] += xs[kk] * w.y;
                acc[j4 * 4 + 2] += xs[kk] * w.z;
                acc[j4 * 4 + 3] += xs[kk] * w.w;
            }
        }
    }
#pragma unroll
    for (int c = 0; c < 16; c++) {
        float4 xv = xr[c];
        float xs[4] = {xv.x, xv.y, xv.z, xv.w};
#pragma unroll
        for (int kk = 0; kk < 4; kk++) {
            int k = c * 4 + kk;
#pragma unroll
            for (int j4 = 0; j4 < 16; j4++) {
                float4 w = *(const float4*)&RW[k * 64 + j4 * 4];
                acc[j4 * 4 + 0] += xs[kk] * w.x;
                acc[j4 * 4 + 1] += xs[kk] * w.y;
                acc[j4 * 4 + 2] += xs[kk] * w.z;
                acc[j4 * 4 + 3] += xs[kk] * w.w;
            }
        }
    }
    float4* yr = (float4*)(xout + (size_t)row * 64);
#pragma unroll
    for (int c = 0; c < 16; c++)
        yr[c] = make_float4(acc[c * 4], acc[c * 4 + 1], acc[c * 4 + 2], acc[c * 4 + 3]);
    if (xhout) {
        __half2* hr = (__half2*)(xhout + (size_t)row * 64);
#pragma unroll
        for (int c = 0; c < 32; c++)
            hr[c] = __halves2half2(__float2half_rn(acc[c * 2]), __float2half_rn(acc[c * 2 + 1]));
    }
}

// ---------- head: r7 structure (1 row/thread, fp32 weights staged in LDS) ----------
__global__ __launch_bounds__(256) void head_kernel(const float* __restrict__ x0, const float* __restrict__ x1,
                            const float* __restrict__ x2, const int* __restrict__ batch,
                            const float* __restrict__ e0w, const float* __restrict__ e0b,
                            const float* __restrict__ e1w, const float* __restrict__ e1b,
                            const float* __restrict__ e2w, const float* __restrict__ e2b,
                            const float* __restrict__ mw, const float* __restrict__ mb,
                            const float* __restrict__ gw, const float* __restrict__ gbp,
                            const float* __restrict__ vw, const float* __restrict__ vb,
                            float* __restrict__ gout, float* __restrict__ vout,
                            unsigned* __restrict__ mkey, int N) {
    __shared__ __align__(16) float EW[3 * 64 * 32];
    __shared__ __align__(16) float MW[96 * 32];
    __shared__ __align__(16) float VW[32 * 32];
    __shared__ float EB[96], MB[32], GW[32], VB[32];
    __shared__ float GB;
    __shared__ unsigned smax[16];
    int t = threadIdx.x;
    for (int i = t; i < 2048; i += 256) { EW[i] = e0w[i]; EW[2048 + i] = e1w[i]; EW[4096 + i] = e2w[i]; }
    for (int i = t; i < 3072; i += 256) MW[i] = mw[i];
    for (int i = t; i < 1024; i += 256) VW[i] = vw[i];
    if (t < 32) { EB[t] = e0b[t]; EB[32 + t] = e1b[t]; EB[64 + t] = e2b[t];
                  MB[t] = mb[t]; GW[t] = gw[t]; VB[t] = vb[t]; }
    if (t == 0) GB = gbp[0];
    if (t < 16) smax[t] = 0u;
    __syncthreads();
    int node = blockIdx.x * 256 + t;
    if (node < N) {
        float xc[32];
#pragma unroll
        for (int j = 0; j < 32; j++) xc[j] = MB[j];
        const float* px[3] = {x0 + (size_t)node * 64, x1 + (size_t)node * 64, x2 + (size_t)node * 64};
        for (int h = 0; h < 3; h++) {
            float e[32];
#pragma unroll
            for (int j = 0; j < 32; j++) e[j] = EB[h * 32 + j];
            const float4* xr = (const float4*)px[h];
#pragma unroll
            for (int c = 0; c < 16; c++) {
                float4 xv = xr[c];
                float xs[4] = {xv.x, xv.y, xv.z, xv.w};
#pragma unroll
                for (int kk = 0; kk < 4; kk++) {
                    int k = c * 4 + kk;
#pragma unroll
                    for (int j4 = 0; j4 < 8; j4++) {
                        float4 w = *(const float4*)&EW[h * 2048 + k * 32 + j4 * 4];
                        e[j4 * 4 + 0] += xs[kk] * w.x;
                        e[j4 * 4 + 1] += xs[kk] * w.y;
                        e[j4 * 4 + 2] += xs[kk] * w.z;
                        e[j4 * 4 + 3] += xs[kk] * w.w;
                    }
                }
            }
#pragma unroll
            for (int j = 0; j < 32; j++) e[j] = fmaxf(e[j], 0.f);
#pragma unroll
            for (int i = 0; i < 32; i++) {
#pragma unroll
                for (int j4 = 0; j4 < 8; j4++) {
                    float4 w = *(const float4*)&MW[(h * 32 + i) * 32 + j4 * 4];
                    xc[j4 * 4 + 0] += e[i] * w.x;
                    xc[j4 * 4 + 1] += e[i] * w.y;
                    xc[j4 * 4 + 2] += e[i] * w.z;
                    xc[j4 * 4 + 3] += e[i] * w.w;
                }
            }
        }
#pragma unroll
        for (int j = 0; j < 32; j++) xc[j] = fmaxf(xc[j], 0.f);
        float g = GB;
#pragma unroll
        for (int i = 0; i < 32; i++) g += xc[i] * GW[i];
        float vv[32];
#pragma unroll
        for (int j = 0; j < 32; j++) vv[j] = VB[j];
#pragma unroll
        for (int i = 0; i < 32; i++) {
#pragma unroll
            for (int j4 = 0; j4 < 8; j4++) {
                float4 w = *(const float4*)&VW[i * 32 + j4 * 4];
                vv[j4 * 4 + 0] += xc[i] * w.x;
                vv[j4 * 4 + 1] += xc[i] * w.y;
                vv[j4 * 4 + 2] += xc[i] * w.z;
                vv[j4 * 4 + 3] += xc[i] * w.w;
            }
        }
        gout[node] = g;
        float4* vr = (float4*)(vout + (size_t)node * 32);
#pragma unroll
        for (int c = 0; c < 8; c++)
            vr[c] = make_float4(vv[c * 4], vv[c * 4 + 1], vv[c * 4 + 2], vv[c * 4 + 3]);
        atomicMax(&smax[batch[node]], fkey(g));
    }
    __syncthreads();
    if (t < 16) atomicMax(&mkey[t], smax[t]);
}

// ---------- pool: d = seg_sum(e), num = seg_sum(e*v) ----------
__global__ __launch_bounds__(256) void pool_kernel(const float* __restrict__ g, const float* __restrict__ v,
                            const int* __restrict__ batch, const unsigned* __restrict__ mkey,
                            float* __restrict__ dsum, float* __restrict__ pooled, int N) {
    __shared__ float sd[16];
    __shared__ float sp[16 * 32];
    __shared__ float sm[16];
    int t = threadIdx.x;
    if (t < 16) { sd[t] = 0.f; sm[t] = funkey(mkey[t]); }
    for (int i = t; i < 512; i += 256) sp[i] = 0.f;
    __syncthreads();
    int node = blockIdx.x * 256 + t;
    if (node < N) {
        int b = batch[node];
        float e = __expf(g[node] - sm[b]);
        atomicAdd(&sd[b], e);
        const float4* vr = (const float4*)(v + (size_t)node * 32);
#pragma unroll
        for (int c = 0; c < 8; c++) {
            float4 vv = vr[c];
            atomicAdd(&sp[b * 32 + c * 4 + 0], e * vv.x);
            atomicAdd(&sp[b * 32 + c * 4 + 1], e * vv.y);
            atomicAdd(&sp[b * 32 + c * 4 + 2], e * vv.z);
            atomicAdd(&sp[b * 32 + c * 4 + 3], e * vv.w);
        }
    }
    __syncthreads();
    if (t < 16) atomicAdd(&dsum[t], sd[t]);
    for (int i = t; i < 512; i += 256) atomicAdd(&pooled[i], sp[i]);
}

// ---------- final: logits + softmax ----------
__global__ __launch_bounds__(64) void final_kernel(const float* __restrict__ dsum, const float* __restrict__ pooled,
                             const float* __restrict__ ow, const float* __restrict__ ob,
                             float* __restrict__ out) {
    int t = threadIdx.x;
    if (t >= 16) return;
    float d = dsum[t];
    float l0 = ob[0], l1 = ob[1];
    for (int i = 0; i < 32; i++) {
        float p = pooled[t * 32 + i] / d;
        l0 += p * ow[i * 2 + 0];
        l1 += p * ow[i * 2 + 1];
    }
    float m = fmaxf(l0, l1);
    float e0 = __expf(l0 - m), e1 = __expf(l1 - m);
    float s = e0 + e1;
    out[t * 2 + 0] = e0 / s;
    out[t * 2 + 1] = e1 / s;
    out[32 + t * 2 + 0] = l0;
    out[32 + t * 2 + 1] = l1;
}

extern "C" void kernel_launch(void* const* d_in, const int* in_sizes, int n_in,
                              void* d_out, int out_size, void* d_ws, size_t ws_size,
                              hipStream_t stream) {
    const float* x       = (const float*)d_in[0];
    const int*   ei      = (const int*)d_in[1];
    const int*   batch   = (const int*)d_in[2];
    const float* lin0_w  = (const float*)d_in[3];
    const float* lin0_b  = (const float*)d_in[4];
    const float* s1_lw   = (const float*)d_in[5];
    const float* s1_lb   = (const float*)d_in[6];
    const float* s1_rw   = (const float*)d_in[7];
    const float* s2_lw   = (const float*)d_in[8];
    const float* s2_lb   = (const float*)d_in[9];
    const float* s2_rw   = (const float*)d_in[10];
    const float* e0w     = (const float*)d_in[11];
    const float* e0b     = (const float*)d_in[12];
    const float* e1w     = (const float*)d_in[13];
    const float* e1b     = (const float*)d_in[14];
    const float* e2w     = (const float*)d_in[15];
    const float* e2b     = (const float*)d_in[16];
    const float* mw      = (const float*)d_in[17];
    const float* mb      = (const float*)d_in[18];
    const float* gw      = (const float*)d_in[19];
    const float* gb      = (const float*)d_in[20];
    const float* vw      = (const float*)d_in[21];
    const float* vb      = (const float*)d_in[22];
    const float* ow      = (const float*)d_in[23];
    const float* ob      = (const float*)d_in[24];
    float* out = (float*)d_out;

    const int N = N_NODES, E = N_EDGES;
    const int* src = ei;
    const int* dst = ei + E;

    // workspace carve
    char* p = (char*)d_ws;
    auto carve = [&](size_t bytes) { char* r = p; p += (bytes + 255) & ~(size_t)255; return (void*)r; };
    float* x0      = (float*)carve((size_t)N * 64 * 4);
    float* x1      = (float*)carve((size_t)N * 64 * 4);
    float* x2      = (float*)carve((size_t)N * 64 * 4);
    __half* x0h    = (__half*)carve((size_t)N * 64 * 2);
    __half* x1h    = (__half*)carve((size_t)N * 64 * 2);
    float* meanb   = (float*)carve((size_t)N * 64 * 4);
    float* vbuf    = (float*)carve((size_t)N * 32 * 4);
    float* gbuf    = (float*)carve((size_t)N * 4);
    int*   csr     = (int*)carve((size_t)E * 4);
    int*   pairs   = (int*)carve((size_t)E * 4);
    int*   h1      = (int*)carve((size_t)B1 * NB1 * 4);
    int*   off1    = (int*)carve((size_t)B1 * NB1 * 4);
    int*   bstart  = (int*)carve((NB1 + 1) * 4);
    int*   rowstart= (int*)carve((size_t)(N + 1) * 4);
    unsigned* mkey = (unsigned*)carve(16 * 4);
    float* dsum    = (float*)carve(16 * 4);
    float* pooled  = (float*)carve(16 * 32 * 4);

    hipMemsetAsync(mkey, 0, 16 * 4, stream);
    hipMemsetAsync(dsum, 0, 16 * 4, stream);
    hipMemsetAsync(pooled, 0, 16 * 32 * 4, stream);

    const int E4 = E / 4;                 // E divisible by 4
    int nbl = (N + 255) / 256;
    int abl = (N + 3) / 4;
    const int NBUCK = (N + 511) >> BSHIFT;   // 196

    hist1_kernel<<<B1, 256, 0, stream>>>(dst, h1, E4);
    scan1_kernel<<<1, 256, 0, stream>>>(h1, off1, bstart, E);
    scatter1_kernel<<<B1, 256, 0, stream>>>(src, dst, off1, pairs, E4);
    bucket_csr_kernel<<<NBUCK, 256, 0, stream>>>(pairs, bstart, rowstart, csr, N, E);

    lin0_kernel<<<nbl, 256, 0, stream>>>(x, lin0_w, lin0_b, x0, x0h, N);

    agg_kernel<<<abl, 256, 0, stream>>>(x0h, rowstart, csr, meanb, N);
    sage_kernel<<<nbl, 256, 0, stream>>>(meanb, x0, s1_lw, s1_lb, s1_rw, x1, x1h, N);

    agg_kernel<<<abl, 256, 0, stream>>>(x1h, rowstart, csr, meanb, N);
    sage_kernel<<<nbl, 256, 0, stream>>>(meanb, x1, s2_lw, s2_lb, s2_rw, x2, (__half*)nullptr, N);

    head_kernel<<<nbl, 256, 0, stream>>>(x0, x1, x2, batch,
                                         e0w, e0b, e1w, e1b, e2w, e2b,
                                         mw, mb, gw, gb, vw, vb,
                                         gbuf, vbuf, mkey, N);

    pool_kernel<<<nbl, 256, 0, stream>>>(gbuf, vbuf, batch, mkey, dsum, pooled, N);

    final_kernel<<<1, 64, 0, stream>>>(dsum, pooled, ow, ob, out);
}